// Round 13
// baseline (376.283 us; speedup 1.0000x reference)
//
#include <hip/hip_runtime.h>
#include <hip/hip_cooperative_groups.h>
#include <math.h>

namespace cg = cooperative_groups;

#define EPSBN 1e-5f

typedef float f32x2 __attribute__((ext_vector_type(2)));
typedef float f32x4 __attribute__((ext_vector_type(4)));

constexpr int B   = 2;
constexpr int C1  = 60;           // x1 channels
constexpr int NV  = 64 * 64 * 64; // voxels per batch
constexpr int NSL = 512;          // coop: slices per batch (512 voxels each)
constexpr int GRID = B * NSL;     // coop grid: 1024 blocks
constexpr int NBa = NV / 1024;    // fallback kA: 256 blocks/batch
constexpr int NBc = NV / 512;     // fallback conv1: 512 blocks/batch

struct Params {
    const float *x1, *x2;
    const float *bn_g, *bn_b, *bn_m, *bn_v;
    const float *cg_w1, *cg_b1, *cg_bng, *cg_bnb, *cg_bnm, *cg_bnv, *cg_w2, *cg_b2;
    const float *sg_w0, *sg_b0, *sg_g0, *sg_be0, *sg_m0, *sg_v0;
    const float *sg_w1, *sg_b1, *sg_g1, *sg_be1, *sg_m1, *sg_v1;
    const float *sg_w2, *sg_b2, *sg_g2, *sg_be2, *sg_m2, *sg_v2;
    const float *sg_w3, *sg_b3;
    float *s0, *s1, *part, *ec, *out0, *outLL;
};

// ===========================================================================
// Cooperative fused kernel: A (DWT+conv0+partials) -> B (conv1+MLP) -> C
// (DWT-recompute + conv2/3 + sigmoid + multiply), grid.sync between phases.
// LDS: sA (16.6KB) aliased between phase A (wsumq) and phase C (esb+dwtb).
// ===========================================================================
__global__ __launch_bounds__(256, 4) void kFused(Params p)
{
    cg::grid_group grid = cg::this_grid();

    const int tid   = threadIdx.x;
    const int slice = blockIdx.x;        // 0..1023
    const int b     = slice >> 9;
    const int sIdx  = slice & 511;
    const int vb    = sIdx * 512;        // base voxel within batch

    __shared__ float  sA[64 * 65];           // phase A: wsumq[c*65+q]; phase C: esb/dwtb
    __shared__ float4 wl4a[108], wl4b[108];  // conv1 / conv2 weights [t*4+r]
    __shared__ float  ecs[64];
    __shared__ float  pooled[64], hmlp[4];

    if (tid < 108) {
        const int t = tid >> 2, r = tid & 3;
        wl4a[tid] = make_float4(p.sg_w1[r*108+t],    p.sg_w1[r*108+27+t],
                                p.sg_w1[r*108+54+t], p.sg_w1[r*108+81+t]);
        wl4b[tid] = make_float4(p.sg_w2[r*108+t],    p.sg_w2[r*108+27+t],
                                p.sg_w2[r*108+54+t], p.sg_w2[r*108+81+t]);
    }

    const int v2 = vb + tid * 2;             // even x; pair of voxels per thread
    const int x = v2 & 63, y = (v2 >> 6) & 63, z = v2 >> 12;

    // ================= Phase A =================
    {
        float dsc[4], dsh[4], c0A[4], c0B[4];
        #pragma unroll
        for (int r = 0; r < 4; ++r) {
            float d = p.bn_g[r] * rsqrtf(p.bn_v[r] + EPSBN);
            dsc[r] = d; dsh[r] = p.bn_b[r] - p.bn_m[r] * d;
            float sc = p.sg_g0[r] * rsqrtf(p.sg_v0[r] + EPSBN);
            c0A[r] = sc; c0B[r] = (p.sg_b0[r] - p.sg_m0[r]) * sc + p.sg_be0[r];
        }

        const float* px2 = p.x2 + (size_t)b * (128*128*64);
        const size_t i00 = ((size_t)(2*z)*128 + 2*y) * 64 + x;
        const float2 p00 = *(const float2*)(px2 + i00);
        const float2 p01 = *(const float2*)(px2 + i00 + 64);
        const float2 p10 = *(const float2*)(px2 + i00 + 8192);
        const float2 p11 = *(const float2*)(px2 + i00 + 8256);
        const float* q00=(const float*)&p00; const float* q01=(const float*)&p01;
        const float* q10=(const float*)&p10; const float* q11=(const float*)&p11;

        float tv[2][4];
        #pragma unroll
        for (int vi = 0; vi < 2; ++vi) {
            float a=q00[vi], bb=q01[vi], c=q10[vi], d=q11[vi];
            float LL=0.5f*(a+bb+c+d), LH=0.5f*(a+bb-c-d);
            float HL=0.5f*(a-bb+c-d), HH=0.5f*(a-bb-c+d);
            tv[vi][0]=fmaxf(LL*dsc[0]+dsh[0],0.f);
            tv[vi][1]=fmaxf(LH*dsc[1]+dsh[1],0.f);
            tv[vi][2]=fmaxf(HL*dsc[2]+dsh[2],0.f);
            tv[vi][3]=fmaxf(HH*dsc[3]+dsh[3],0.f);
        }

        float acc[2][4] = {};
        #pragma unroll
        for (int c = 0; c < 4; ++c) {
            #pragma unroll
            for (int vi = 0; vi < 2; ++vi) {
                float t = tv[vi][c];
                #pragma unroll
                for (int r = 0; r < 4; ++r) acc[vi][r] += p.sg_w0[r*64+c] * t;
            }
            float rs = tv[0][c] + tv[1][c];
            rs += __shfl_xor(rs, 1);
            rs += __shfl_xor(rs, 2);
            if ((tid & 3) == 0) sA[c*65 + (tid >> 2)] = rs;
        }

        const float* px1 = p.x1 + (size_t)b * C1 * NV + v2;
        #pragma unroll 4
        for (int c = 0; c < C1; ++c) {
            const float2 f = *(const float2*)(px1 + (size_t)c * NV);
            #pragma unroll
            for (int r = 0; r < 4; ++r) {
                const float w = p.sg_w0[r*64+4+c];   // uniform -> s_load
                acc[0][r] += w * f.x;
                acc[1][r] += w * f.y;
            }
            float rs = f.x + f.y;
            rs += __shfl_xor(rs, 1);
            rs += __shfl_xor(rs, 2);
            if ((tid & 3) == 0) sA[(4+c)*65 + (tid >> 2)] = rs;
        }

        float4* ps0 = (float4*)p.s0 + (size_t)b * NV + v2;
        #pragma unroll
        for (int vi = 0; vi < 2; ++vi)
            ps0[vi] = make_float4(fmaxf(acc[vi][0]*c0A[0]+c0B[0],0.f),
                                  fmaxf(acc[vi][1]*c0A[1]+c0B[1],0.f),
                                  fmaxf(acc[vi][2]*c0A[2]+c0B[2],0.f),
                                  fmaxf(acc[vi][3]*c0A[3]+c0B[3],0.f));
        __syncthreads();
        if (tid < 64) {
            const float* rowp = &sA[tid*65];
            float s = 0.f;
            #pragma unroll
            for (int i = 0; i < 64; ++i) s += rowp[i];
            p.part[((size_t)b*64 + tid) * NSL + sIdx] = s;
        }
    }

    grid.sync();

    // ================= Phase B: conv1 (+ MLP on sIdx==0) =================
    {
        float cAr[4], cBr[4];
        #pragma unroll
        for (int r = 0; r < 4; ++r) {
            float sc = p.sg_g1[r] * rsqrtf(p.sg_v1[r] + EPSBN);
            cAr[r] = sc;
            cBr[r] = (p.sg_b1[r] - p.sg_m1[r]) * sc + p.sg_be1[r];
        }
        const float4* pin = (const float4*)p.s0 + (size_t)b * NV;
        float acc[2][4] = {};
        #pragma unroll
        for (int kz = -1; kz <= 1; ++kz) {
            const int zz = z + 4*kz;
            if ((unsigned)zz >= 64u) continue;
            #pragma unroll
            for (int ky = -1; ky <= 1; ++ky) {
                const int yy = y + 4*ky;
                if ((unsigned)yy >= 64u) continue;
                #pragma unroll
                for (int kx = -1; kx <= 1; ++kx) {
                    const int xx = x + 4*kx;      // x even -> xx+1 in-bounds iff xx is
                    if ((unsigned)xx >= 64u) continue;
                    const int t = (kz+1)*9 + (ky+1)*3 + (kx+1);
                    const int vt = zz*4096 + yy*64 + xx;
                    const float4 w0 = wl4a[t*4+0], w1 = wl4a[t*4+1];
                    const float4 w2 = wl4a[t*4+2], w3 = wl4a[t*4+3];
                    #pragma unroll
                    for (int vi = 0; vi < 2; ++vi) {
                        const float4 tap = pin[vt + vi];
                        acc[vi][0] += w0.x*tap.x + w0.y*tap.y + w0.z*tap.z + w0.w*tap.w;
                        acc[vi][1] += w1.x*tap.x + w1.y*tap.y + w1.z*tap.z + w1.w*tap.w;
                        acc[vi][2] += w2.x*tap.x + w2.y*tap.y + w2.z*tap.z + w2.w*tap.w;
                        acc[vi][3] += w3.x*tap.x + w3.y*tap.y + w3.z*tap.z + w3.w*tap.w;
                    }
                }
            }
        }
        float4* po = (float4*)p.s1 + (size_t)b * NV + v2;
        #pragma unroll
        for (int vi = 0; vi < 2; ++vi)
            po[vi] = make_float4(fmaxf(acc[vi][0]*cAr[0]+cBr[0],0.f),
                                 fmaxf(acc[vi][1]*cAr[1]+cBr[1],0.f),
                                 fmaxf(acc[vi][2]*cAr[2]+cBr[2],0.f),
                                 fmaxf(acc[vi][3]*cAr[3]+cBr[3],0.f));

        if (sIdx == 0) {
            const int c = tid >> 2, q = tid & 3;
            const float4* pp = (const float4*)(p.part + ((size_t)b*64 + c) * NSL + q*128);
            float sm = 0.f;
            #pragma unroll
            for (int i = 0; i < 32; ++i) { float4 f = pp[i]; sm += f.x+f.y+f.z+f.w; }
            sm += __shfl_xor(sm, 1);
            sm += __shfl_xor(sm, 2);
            if (q == 0) pooled[c] = sm * (1.0f / NV);
            __syncthreads();
            if (tid < 4) {
                float a = p.cg_b1[tid];
                for (int cc = 0; cc < 64; ++cc) a += pooled[cc] * p.cg_w1[tid*64+cc];
                float sc = p.cg_bng[tid] * rsqrtf(p.cg_bnv[tid] + EPSBN);
                hmlp[tid] = fmaxf((a - p.cg_bnm[tid]) * sc + p.cg_bnb[tid], 0.f);
            }
            __syncthreads();
            if (tid < 64) {
                float a = p.cg_b2[tid];
                #pragma unroll
                for (int r = 0; r < 4; ++r) a += hmlp[r] * p.cg_w2[tid*4+r];
                p.ec[b*64 + tid] = __expf(-a);
            }
        }
    }

    grid.sync();

    // ================= Phase C =================
    float* esb = sA;                           // [512]
    float (*dwtb)[4] = (float(*)[4])(sA + 512); // [512][4]
    if (tid < 64) ecs[tid] = p.ec[b*64 + tid];
    {
        float cAr[4], cBr[4], w3l[4], dsc[4], dsh[4];
        #pragma unroll
        for (int r = 0; r < 4; ++r) {
            float sc = p.sg_g2[r] * rsqrtf(p.sg_v2[r] + EPSBN);
            cAr[r] = sc;
            cBr[r] = (p.sg_b2[r] - p.sg_m2[r]) * sc + p.sg_be2[r];
            w3l[r] = p.sg_w3[r];
            float d = p.bn_g[r] * rsqrtf(p.bn_v[r] + EPSBN);
            dsc[r] = d; dsh[r] = p.bn_b[r] - p.bn_m[r] * d;
        }
        const float b3l = p.sg_b3[0];

        const float* px2 = p.x2 + (size_t)b * (128*128*64);
        const size_t i00 = ((size_t)(2*z)*128 + 2*y) * 64 + x;
        const float2 p00 = *(const float2*)(px2 + i00);
        const float2 p01 = *(const float2*)(px2 + i00 + 64);
        const float2 p10 = *(const float2*)(px2 + i00 + 8192);
        const float2 p11 = *(const float2*)(px2 + i00 + 8256);
        const float* q00=(const float*)&p00; const float* q01=(const float*)&p01;
        const float* q10=(const float*)&p10; const float* q11=(const float*)&p11;
        float llv[2];
        #pragma unroll
        for (int vi = 0; vi < 2; ++vi) {
            float a=q00[vi], bb=q01[vi], c=q10[vi], d=q11[vi];
            float LL=0.5f*(a+bb+c+d), LH=0.5f*(a+bb-c-d);
            float HL=0.5f*(a-bb+c-d), HH=0.5f*(a-bb-c+d);
            llv[vi] = LL;
            float4 tv = make_float4(fmaxf(LL*dsc[0]+dsh[0],0.f), fmaxf(LH*dsc[1]+dsh[1],0.f),
                                    fmaxf(HL*dsc[2]+dsh[2],0.f), fmaxf(HH*dsc[3]+dsh[3],0.f));
            *(float4*)&dwtb[tid*2+vi][0] = tv;
        }
        {
            f32x2 ll2 = { llv[0], llv[1] };
            __builtin_nontemporal_store(ll2, (f32x2*)(p.outLL + (size_t)b*NV + v2));
        }

        const float4* pin = (const float4*)p.s1 + (size_t)b * NV;
        float acc[2][4] = {};
        #pragma unroll
        for (int kz = -1; kz <= 1; ++kz) {
            const int zz = z + 4*kz;
            if ((unsigned)zz >= 64u) continue;
            #pragma unroll
            for (int ky = -1; ky <= 1; ++ky) {
                const int yy = y + 4*ky;
                if ((unsigned)yy >= 64u) continue;
                #pragma unroll
                for (int kx = -1; kx <= 1; ++kx) {
                    const int xx = x + 4*kx;
                    if ((unsigned)xx >= 64u) continue;
                    const int t = (kz+1)*9 + (ky+1)*3 + (kx+1);
                    const int vt = zz*4096 + yy*64 + xx;
                    const float4 w0 = wl4b[t*4+0], w1 = wl4b[t*4+1];
                    const float4 w2 = wl4b[t*4+2], w3q = wl4b[t*4+3];
                    #pragma unroll
                    for (int vi = 0; vi < 2; ++vi) {
                        const float4 tap = pin[vt + vi];
                        acc[vi][0] += w0.x*tap.x + w0.y*tap.y + w0.z*tap.z + w0.w*tap.w;
                        acc[vi][1] += w1.x*tap.x + w1.y*tap.y + w1.z*tap.z + w1.w*tap.w;
                        acc[vi][2] += w2.x*tap.x + w2.y*tap.y + w2.z*tap.z + w2.w*tap.w;
                        acc[vi][3] += w3q.x*tap.x + w3q.y*tap.y + w3q.z*tap.z + w3q.w*tap.w;
                    }
                }
            }
        }
        #pragma unroll
        for (int vi = 0; vi < 2; ++vi) {
            float r0 = fmaxf(acc[vi][0]*cAr[0]+cBr[0],0.f);
            float r1 = fmaxf(acc[vi][1]*cAr[1]+cBr[1],0.f);
            float r2 = fmaxf(acc[vi][2]*cAr[2]+cBr[2],0.f);
            float r3 = fmaxf(acc[vi][3]*cAr[3]+cBr[3],0.f);
            esb[tid*2+vi] = __expf(-(b3l + w3l[0]*r0 + w3l[1]*r1 + w3l[2]*r2 + w3l[3]*r3));
        }
    }
    __syncthreads();

    {
        const int q = tid & 127;
        const int v4 = vb + q * 4;
        const int ch0 = (tid >> 7) * 32;
        const float es0 = esb[q*4+0], es1 = esb[q*4+1];
        const float es2 = esb[q*4+2], es3 = esb[q*4+3];
        float* po = p.out0 + ((size_t)b*64 + ch0) * NV + v4;

        if (ch0 == 0) {      // wave-uniform
            float4 dq0 = *(const float4*)&dwtb[q*4+0][0];
            float4 dq1 = *(const float4*)&dwtb[q*4+1][0];
            float4 dq2 = *(const float4*)&dwtb[q*4+2][0];
            float4 dq3 = *(const float4*)&dwtb[q*4+3][0];
            const float dv0[4] = { dq0.x, dq0.y, dq0.z, dq0.w };
            const float dv1[4] = { dq1.x, dq1.y, dq1.z, dq1.w };
            const float dv2[4] = { dq2.x, dq2.y, dq2.z, dq2.w };
            const float dv3[4] = { dq3.x, dq3.y, dq3.z, dq3.w };
            #pragma unroll
            for (int cc = 0; cc < 4; ++cc) {
                const float e = ecs[cc];
                f32x4 o;
                o.x = dv0[cc] * (1.f + __builtin_amdgcn_rcpf(1.f + e*es0));
                o.y = dv1[cc] * (1.f + __builtin_amdgcn_rcpf(1.f + e*es1));
                o.z = dv2[cc] * (1.f + __builtin_amdgcn_rcpf(1.f + e*es2));
                o.w = dv3[cc] * (1.f + __builtin_amdgcn_rcpf(1.f + e*es3));
                __builtin_nontemporal_store(o, (f32x4*)(po + (size_t)cc * NV));
            }
            const float* px = p.x1 + (size_t)b * C1 * NV + v4;
            #pragma unroll 7
            for (int cc = 4; cc < 32; ++cc) {
                const float4 in4 = *(const float4*)(px + (size_t)(cc-4) * NV);
                const float e = ecs[cc];
                f32x4 o;
                o.x = in4.x * (1.f + __builtin_amdgcn_rcpf(1.f + e*es0));
                o.y = in4.y * (1.f + __builtin_amdgcn_rcpf(1.f + e*es1));
                o.z = in4.z * (1.f + __builtin_amdgcn_rcpf(1.f + e*es2));
                o.w = in4.w * (1.f + __builtin_amdgcn_rcpf(1.f + e*es3));
                __builtin_nontemporal_store(o, (f32x4*)(po + (size_t)cc * NV));
            }
        } else {
            const float* px = p.x1 + ((size_t)b * C1 + 28) * NV + v4;
            #pragma unroll 8
            for (int cc = 0; cc < 32; ++cc) {
                const float4 in4 = *(const float4*)(px + (size_t)cc * NV);
                const float e = ecs[32 + cc];
                f32x4 o;
                o.x = in4.x * (1.f + __builtin_amdgcn_rcpf(1.f + e*es0));
                o.y = in4.y * (1.f + __builtin_amdgcn_rcpf(1.f + e*es1));
                o.z = in4.z * (1.f + __builtin_amdgcn_rcpf(1.f + e*es2));
                o.w = in4.w * (1.f + __builtin_amdgcn_rcpf(1.f + e*es3));
                __builtin_nontemporal_store(o, (f32x4*)(po + (size_t)cc * NV));
            }
        }
    }
}

// ===========================================================================
// Fallback path — round-11 kernels (proven 99.3 us).
// ===========================================================================
__global__ __launch_bounds__(256) void kA(
    const float* __restrict__ x1, const float* __restrict__ x2,
    const float* __restrict__ bn_g, const float* __restrict__ bn_b,
    const float* __restrict__ bn_m, const float* __restrict__ bn_v,
    const float* __restrict__ sg_w0, const float* __restrict__ sg_b0,
    const float* __restrict__ sg_g0, const float* __restrict__ sg_be0,
    const float* __restrict__ sg_m0, const float* __restrict__ sg_v0,
    float* __restrict__ s0,
    float* __restrict__ part)
{
    __shared__ float wsumq[64][65];

    const int tid = threadIdx.x;
    const int qid = tid >> 2;

    float dsc[4], dsh[4], c0A[4], c0B[4];
    #pragma unroll
    for (int r = 0; r < 4; ++r) {
        float d = bn_g[r] * rsqrtf(bn_v[r] + EPSBN);
        dsc[r] = d; dsh[r] = bn_b[r] - bn_m[r] * d;
        float sc = sg_g0[r] * rsqrtf(sg_v0[r] + EPSBN);
        c0A[r] = sc; c0B[r] = (sg_b0[r] - sg_m0[r]) * sc + sg_be0[r];
    }

    const int b = blockIdx.y;
    const int v = blockIdx.x * 1024 + tid * 4;
    const int x = v & 63, y = (v >> 6) & 63, z = v >> 12;

    const float* px2 = x2 + (size_t)b * (128 * 128 * 64);
    const size_t i00 = ((size_t)(2 * z) * 128 + 2 * y) * 64 + x;
    const float4 p00 = *(const float4*)(px2 + i00);
    const float4 p01 = *(const float4*)(px2 + i00 + 64);
    const float4 p10 = *(const float4*)(px2 + i00 + 8192);
    const float4 p11 = *(const float4*)(px2 + i00 + 8256);
    const float* q00 = (const float*)&p00; const float* q01 = (const float*)&p01;
    const float* q10 = (const float*)&p10; const float* q11 = (const float*)&p11;

    float tv[4][4];
    #pragma unroll
    for (int vi = 0; vi < 4; ++vi) {
        float a = q00[vi], bb = q01[vi], c = q10[vi], d = q11[vi];
        float LL = 0.5f * (a + bb + c + d);
        float LH = 0.5f * (a + bb - c - d);
        float HL = 0.5f * (a - bb + c - d);
        float HH = 0.5f * (a - bb - c + d);
        tv[vi][0] = fmaxf(LL * dsc[0] + dsh[0], 0.f);
        tv[vi][1] = fmaxf(LH * dsc[1] + dsh[1], 0.f);
        tv[vi][2] = fmaxf(HL * dsc[2] + dsh[2], 0.f);
        tv[vi][3] = fmaxf(HH * dsc[3] + dsh[3], 0.f);
    }

    float acc[4][4] = {};
    #pragma unroll
    for (int c = 0; c < 4; ++c) {
        #pragma unroll
        for (int vi = 0; vi < 4; ++vi) {
            float t = tv[vi][c];
            #pragma unroll
            for (int r = 0; r < 4; ++r) acc[vi][r] += sg_w0[r * 64 + c] * t;
        }
        float rs = tv[0][c] + tv[1][c] + tv[2][c] + tv[3][c];
        rs += __shfl_xor(rs, 1);
        rs += __shfl_xor(rs, 2);
        if ((tid & 3) == 0) wsumq[c][qid] = rs;
    }

    const float* px1 = x1 + (size_t)b * C1 * NV + v;
    #pragma unroll 4
    for (int c = 0; c < C1; ++c) {
        const float4 f = *(const float4*)(px1 + (size_t)c * NV);
        const float* fv = (const float*)&f;
        #pragma unroll
        for (int r = 0; r < 4; ++r) {
            const float w = sg_w0[r * 64 + 4 + c];
            #pragma unroll
            for (int vi = 0; vi < 4; ++vi) acc[vi][r] += w * fv[vi];
        }
        float rs = f.x + f.y + f.z + f.w;
        rs += __shfl_xor(rs, 1);
        rs += __shfl_xor(rs, 2);
        if ((tid & 3) == 0) wsumq[4 + c][qid] = rs;
    }

    float4* ps0 = (float4*)s0 + (size_t)b * NV + v;
    #pragma unroll
    for (int vi = 0; vi < 4; ++vi)
        ps0[vi] = make_float4(fmaxf(acc[vi][0] * c0A[0] + c0B[0], 0.f),
                              fmaxf(acc[vi][1] * c0A[1] + c0B[1], 0.f),
                              fmaxf(acc[vi][2] * c0A[2] + c0B[2], 0.f),
                              fmaxf(acc[vi][3] * c0A[3] + c0B[3], 0.f));

    __syncthreads();
    if (tid < 64) {
        const float* rowp = &wsumq[tid][0];
        float p = 0.f;
        #pragma unroll
        for (int i = 0; i < 64; ++i) p += rowp[i];
        part[((size_t)b * 64 + tid) * NBa + blockIdx.x] = p;
    }
}

__global__ __launch_bounds__(256) void kConv1(
    const float* __restrict__ sin_,
    const float* __restrict__ w, const float* __restrict__ bias,
    const float* __restrict__ g, const float* __restrict__ be,
    const float* __restrict__ m, const float* __restrict__ vv,
    const float* __restrict__ part,
    const float* __restrict__ cg_w1, const float* __restrict__ cg_b1,
    const float* __restrict__ cg_bng, const float* __restrict__ cg_bnb,
    const float* __restrict__ cg_bnm, const float* __restrict__ cg_bnv,
    const float* __restrict__ cg_w2, const float* __restrict__ cg_b2,
    float* __restrict__ ec,
    float* __restrict__ outp)
{
    const int tid = threadIdx.x;
    const int b = blockIdx.y;

    if (blockIdx.x == NBc) {
        __shared__ float pooled[64];
        __shared__ float h[4];
        const int c = tid >> 2, q = tid & 3;
        const float4* pp = (const float4*)(part + ((size_t)b * 64 + c) * NBa + q * 64);
        float sm = 0.f;
        #pragma unroll
        for (int i = 0; i < 16; ++i) { float4 f = pp[i]; sm += f.x + f.y + f.z + f.w; }
        sm += __shfl_xor(sm, 1);
        sm += __shfl_xor(sm, 2);
        if (q == 0) pooled[c] = sm * (1.0f / NV);
        __syncthreads();
        if (tid < 4) {
            float a = cg_b1[tid];
            for (int cc = 0; cc < 64; ++cc) a += pooled[cc] * cg_w1[tid * 64 + cc];
            float sc = cg_bng[tid] * rsqrtf(cg_bnv[tid] + EPSBN);
            h[tid] = fmaxf((a - cg_bnm[tid]) * sc + cg_bnb[tid], 0.f);
        }
        __syncthreads();
        if (tid < 64) {
            float a = cg_b2[tid];
            #pragma unroll
            for (int r = 0; r < 4; ++r) a += h[r] * cg_w2[tid * 4 + r];
            ec[b * 64 + tid] = __expf(-a);
        }
        return;
    }

    __shared__ float4 wl4[108];
    if (tid < 108) {
        const int t = tid >> 2, r = tid & 3;
        wl4[tid] = make_float4(w[r * 108 +      t], w[r * 108 +  27 + t],
                               w[r * 108 + 54 + t], w[r * 108 +  81 + t]);
    }
    float cAr[4], cBr[4];
    #pragma unroll
    for (int r = 0; r < 4; ++r) {
        float sc = g[r] * rsqrtf(vv[r] + EPSBN);
        cAr[r] = sc;
        cBr[r] = (bias[r] - m[r]) * sc + be[r];
    }
    __syncthreads();

    const int v = blockIdx.x * 512 + tid * 2;
    const int x = v & 63, y = (v >> 6) & 63, z = v >> 12;
    const float4* pin = (const float4*)sin_ + (size_t)b * NV;

    float acc[2][4] = {};
    #pragma unroll
    for (int kz = -1; kz <= 1; ++kz) {
        const int zz = z + 4 * kz;
        if ((unsigned)zz >= 64u) continue;
        #pragma unroll
        for (int ky = -1; ky <= 1; ++ky) {
            const int yy = y + 4 * ky;
            if ((unsigned)yy >= 64u) continue;
            #pragma unroll
            for (int kx = -1; kx <= 1; ++kx) {
                const int xx = x + 4 * kx;
                if ((unsigned)xx >= 64u) continue;
                const int t = (kz + 1) * 9 + (ky + 1) * 3 + (kx + 1);
                const int vt = zz * 4096 + yy * 64 + xx;
                const float4 w0 = wl4[t * 4 + 0];
                const float4 w1 = wl4[t * 4 + 1];
                const float4 w2 = wl4[t * 4 + 2];
                const float4 w3 = wl4[t * 4 + 3];
                #pragma unroll
                for (int vi = 0; vi < 2; ++vi) {
                    const float4 tap = pin[vt + vi];
                    acc[vi][0] += w0.x * tap.x + w0.y * tap.y + w0.z * tap.z + w0.w * tap.w;
                    acc[vi][1] += w1.x * tap.x + w1.y * tap.y + w1.z * tap.z + w1.w * tap.w;
                    acc[vi][2] += w2.x * tap.x + w2.y * tap.y + w2.z * tap.z + w2.w * tap.w;
                    acc[vi][3] += w3.x * tap.x + w3.y * tap.y + w3.z * tap.z + w3.w * tap.w;
                }
            }
        }
    }

    float4* po = (float4*)outp + (size_t)b * NV + v;
    #pragma unroll
    for (int vi = 0; vi < 2; ++vi)
        po[vi] = make_float4(fmaxf(acc[vi][0] * cAr[0] + cBr[0], 0.f),
                             fmaxf(acc[vi][1] * cAr[1] + cBr[1], 0.f),
                             fmaxf(acc[vi][2] * cAr[2] + cBr[2], 0.f),
                             fmaxf(acc[vi][3] * cAr[3] + cBr[3], 0.f));
}

__global__ __launch_bounds__(256) void kMulF(
    const float* __restrict__ x1,
    const float* __restrict__ x2,
    const float* __restrict__ bn_g, const float* __restrict__ bn_b,
    const float* __restrict__ bn_m, const float* __restrict__ bn_v,
    const float* __restrict__ s1,
    const float* __restrict__ w, const float* __restrict__ bias,
    const float* __restrict__ g, const float* __restrict__ be,
    const float* __restrict__ m, const float* __restrict__ vv,
    const float* __restrict__ w3, const float* __restrict__ b3,
    const float* __restrict__ ec,
    float* __restrict__ out0,
    float* __restrict__ outLL)
{
    const int tid = threadIdx.x;
    const int b = blockIdx.x >> 9;
    const int vb = (blockIdx.x & 511) * 512;

    __shared__ float4 wl4[108];
    __shared__ float ecs[64];
    __shared__ float esb[512];
    __shared__ float dwtb[512][4];
    if (tid < 108) {
        const int t = tid >> 2, r = tid & 3;
        wl4[tid] = make_float4(w[r * 108 +      t], w[r * 108 +  27 + t],
                               w[r * 108 + 54 + t], w[r * 108 +  81 + t]);
    }
    if (tid < 64) ecs[tid] = ec[b * 64 + tid];
    float cAr[4], cBr[4], w3l[4], dsc[4], dsh[4];
    #pragma unroll
    for (int r = 0; r < 4; ++r) {
        float sc = g[r] * rsqrtf(vv[r] + EPSBN);
        cAr[r] = sc;
        cBr[r] = (bias[r] - m[r]) * sc + be[r];
        w3l[r] = w3[r];
        float d = bn_g[r] * rsqrtf(bn_v[r] + EPSBN);
        dsc[r] = d; dsh[r] = bn_b[r] - bn_m[r] * d;
    }
    const float b3l = b3[0];
    __syncthreads();

    {
        const int v = vb + tid * 2;
        const int x = v & 63, y = (v >> 6) & 63, z = v >> 12;

        const float* px2 = x2 + (size_t)b * (128 * 128 * 64);
        const size_t i00 = ((size_t)(2 * z) * 128 + 2 * y) * 64 + x;
        const float2 p00 = *(const float2*)(px2 + i00);
        const float2 p01 = *(const float2*)(px2 + i00 + 64);
        const float2 p10 = *(const float2*)(px2 + i00 + 8192);
        const float2 p11 = *(const float2*)(px2 + i00 + 8256);
        const float* q00 = (const float*)&p00; const float* q01 = (const float*)&p01;
        const float* q10 = (const float*)&p10; const float* q11 = (const float*)&p11;
        float llv[2];
        #pragma unroll
        for (int vi = 0; vi < 2; ++vi) {
            float a = q00[vi], bb = q01[vi], c = q10[vi], d = q11[vi];
            float LL = 0.5f * (a + bb + c + d);
            float LH = 0.5f * (a + bb - c - d);
            float HL = 0.5f * (a - bb + c - d);
            float HH = 0.5f * (a - bb - c + d);
            llv[vi] = LL;
            float4 tv = make_float4(fmaxf(LL * dsc[0] + dsh[0], 0.f),
                                    fmaxf(LH * dsc[1] + dsh[1], 0.f),
                                    fmaxf(HL * dsc[2] + dsh[2], 0.f),
                                    fmaxf(HH * dsc[3] + dsh[3], 0.f));
            *(float4*)&dwtb[tid * 2 + vi][0] = tv;
        }
        {
            f32x2 ll2 = { llv[0], llv[1] };
            __builtin_nontemporal_store(ll2, (f32x2*)(outLL + (size_t)b * NV + v));
        }

        const float4* pin = (const float4*)s1 + (size_t)b * NV;
        float acc[2][4] = {};
        #pragma unroll
        for (int kz = -1; kz <= 1; ++kz) {
            const int zz = z + 4 * kz;
            if ((unsigned)zz >= 64u) continue;
            #pragma unroll
            for (int ky = -1; ky <= 1; ++ky) {
                const int yy = y + 4 * ky;
                if ((unsigned)yy >= 64u) continue;
                #pragma unroll
                for (int kx = -1; kx <= 1; ++kx) {
                    const int xx = x + 4 * kx;
                    if ((unsigned)xx >= 64u) continue;
                    const int t = (kz + 1) * 9 + (ky + 1) * 3 + (kx + 1);
                    const int vt = zz * 4096 + yy * 64 + xx;
                    const float4 w0 = wl4[t * 4 + 0];
                    const float4 w1 = wl4[t * 4 + 1];
                    const float4 w2 = wl4[t * 4 + 2];
                    const float4 w3q = wl4[t * 4 + 3];
                    #pragma unroll
                    for (int vi = 0; vi < 2; ++vi) {
                        const float4 tap = pin[vt + vi];
                        acc[vi][0] += w0.x * tap.x + w0.y * tap.y + w0.z * tap.z + w0.w * tap.w;
                        acc[vi][1] += w1.x * tap.x + w1.y * tap.y + w1.z * tap.z + w1.w * tap.w;
                        acc[vi][2] += w2.x * tap.x + w2.y * tap.y + w2.z * tap.z + w2.w * tap.w;
                        acc[vi][3] += w3q.x * tap.x + w3q.y * tap.y + w3q.z * tap.z + w3q.w * tap.w;
                    }
                }
            }
        }
        #pragma unroll
        for (int vi = 0; vi < 2; ++vi) {
            float r0 = fmaxf(acc[vi][0] * cAr[0] + cBr[0], 0.f);
            float r1 = fmaxf(acc[vi][1] * cAr[1] + cBr[1], 0.f);
            float r2 = fmaxf(acc[vi][2] * cAr[2] + cBr[2], 0.f);
            float r3 = fmaxf(acc[vi][3] * cAr[3] + cBr[3], 0.f);
            esb[tid * 2 + vi] =
                __expf(-(b3l + w3l[0] * r0 + w3l[1] * r1 + w3l[2] * r2 + w3l[3] * r3));
        }
    }
    __syncthreads();

    const int q = tid & 127;
    const int v = vb + q * 4;
    const int ch0 = (tid >> 7) * 32;
    const float es0 = esb[q * 4 + 0], es1 = esb[q * 4 + 1];
    const float es2 = esb[q * 4 + 2], es3 = esb[q * 4 + 3];

    float* po = out0 + ((size_t)b * 64 + ch0) * NV + v;

    if (ch0 == 0) {
        float4 dq0 = *(const float4*)&dwtb[q * 4 + 0][0];
        float4 dq1 = *(const float4*)&dwtb[q * 4 + 1][0];
        float4 dq2 = *(const float4*)&dwtb[q * 4 + 2][0];
        float4 dq3 = *(const float4*)&dwtb[q * 4 + 3][0];
        const float dv0[4] = { dq0.x, dq0.y, dq0.z, dq0.w };
        const float dv1[4] = { dq1.x, dq1.y, dq1.z, dq1.w };
        const float dv2[4] = { dq2.x, dq2.y, dq2.z, dq2.w };
        const float dv3[4] = { dq3.x, dq3.y, dq3.z, dq3.w };
        #pragma unroll
        for (int cc = 0; cc < 4; ++cc) {
            const float e = ecs[cc];
            f32x4 o;
            o.x = dv0[cc] * (1.f + __builtin_amdgcn_rcpf(1.f + e * es0));
            o.y = dv1[cc] * (1.f + __builtin_amdgcn_rcpf(1.f + e * es1));
            o.z = dv2[cc] * (1.f + __builtin_amdgcn_rcpf(1.f + e * es2));
            o.w = dv3[cc] * (1.f + __builtin_amdgcn_rcpf(1.f + e * es3));
            __builtin_nontemporal_store(o, (f32x4*)(po + (size_t)cc * NV));
        }
        const float* px = x1 + (size_t)b * C1 * NV + v;
        #pragma unroll 7
        for (int cc = 4; cc < 32; ++cc) {
            const float4 in4 = *(const float4*)(px + (size_t)(cc - 4) * NV);
            const float e = ecs[cc];
            f32x4 o;
            o.x = in4.x * (1.f + __builtin_amdgcn_rcpf(1.f + e * es0));
            o.y = in4.y * (1.f + __builtin_amdgcn_rcpf(1.f + e * es1));
            o.z = in4.z * (1.f + __builtin_amdgcn_rcpf(1.f + e * es2));
            o.w = in4.w * (1.f + __builtin_amdgcn_rcpf(1.f + e * es3));
            __builtin_nontemporal_store(o, (f32x4*)(po + (size_t)cc * NV));
        }
    } else {
        const float* px = x1 + ((size_t)b * C1 + 28) * NV + v;
        #pragma unroll 8
        for (int cc = 0; cc < 32; ++cc) {
            const float4 in4 = *(const float4*)(px + (size_t)cc * NV);
            const float e = ecs[32 + cc];
            f32x4 o;
            o.x = in4.x * (1.f + __builtin_amdgcn_rcpf(1.f + e * es0));
            o.y = in4.y * (1.f + __builtin_amdgcn_rcpf(1.f + e * es1));
            o.z = in4.z * (1.f + __builtin_amdgcn_rcpf(1.f + e * es2));
            o.w = in4.w * (1.f + __builtin_amdgcn_rcpf(1.f + e * es3));
            __builtin_nontemporal_store(o, (f32x4*)(po + (size_t)cc * NV));
        }
    }
}

// ---------------------------------------------------------------------------
extern "C" void kernel_launch(void* const* d_in, const int* in_sizes, int n_in,
                              void* d_out, int out_size, void* d_ws, size_t ws_size,
                              hipStream_t stream)
{
    float* ws = (float*)d_ws;
    float* out0  = (float*)d_out;

    Params p;
    p.x1 = (const float*)d_in[0];
    p.x2 = (const float*)d_in[1];
    p.bn_g = (const float*)d_in[2];
    p.bn_b = (const float*)d_in[3];
    p.bn_m = (const float*)d_in[4];
    p.bn_v = (const float*)d_in[5];
    p.cg_w1 = (const float*)d_in[6];
    p.cg_b1 = (const float*)d_in[7];
    p.cg_bng = (const float*)d_in[8];
    p.cg_bnb = (const float*)d_in[9];
    p.cg_bnm = (const float*)d_in[10];
    p.cg_bnv = (const float*)d_in[11];
    p.cg_w2 = (const float*)d_in[12];
    p.cg_b2 = (const float*)d_in[13];
    p.sg_w0 = (const float*)d_in[14];
    p.sg_b0 = (const float*)d_in[15];
    p.sg_g0 = (const float*)d_in[16];
    p.sg_be0 = (const float*)d_in[17];
    p.sg_m0 = (const float*)d_in[18];
    p.sg_v0 = (const float*)d_in[19];
    p.sg_w1 = (const float*)d_in[20];
    p.sg_b1 = (const float*)d_in[21];
    p.sg_g1 = (const float*)d_in[22];
    p.sg_be1 = (const float*)d_in[23];
    p.sg_m1 = (const float*)d_in[24];
    p.sg_v1 = (const float*)d_in[25];
    p.sg_w2 = (const float*)d_in[26];
    p.sg_b2 = (const float*)d_in[27];
    p.sg_g2 = (const float*)d_in[28];
    p.sg_be2 = (const float*)d_in[29];
    p.sg_m2 = (const float*)d_in[30];
    p.sg_v2 = (const float*)d_in[31];
    p.sg_w3 = (const float*)d_in[32];
    p.sg_b3 = (const float*)d_in[33];

    p.s0   = ws;                    // 2,097,152 floats
    p.s1   = ws + 2097152;          // 2,097,152
    p.part = ws + 4194304;          // coop: B*64*NSL = 65,536 (fallback uses NBa stride)
    p.ec   = ws + 4259840;          // 128
    p.out0  = out0;
    p.outLL = out0 + (size_t)B * 64 * NV;

    void* args[] = { &p };
    hipError_t err = hipLaunchCooperativeKernel((const void*)kFused, dim3(GRID), dim3(256),
                                                args, 0, stream);
    if (err != hipSuccess) {
        (void)hipGetLastError();   // clear sticky error, then proven 3-kernel path
        dim3 blk(256);
        kA<<<dim3(NBa, B), blk, 0, stream>>>(p.x1, p.x2, p.bn_g, p.bn_b, p.bn_m, p.bn_v,
                                             p.sg_w0, p.sg_b0, p.sg_g0, p.sg_be0, p.sg_m0, p.sg_v0,
                                             p.s0, p.part);
        kConv1<<<dim3(NBc + 1, B), blk, 0, stream>>>(p.s0, p.sg_w1, p.sg_b1, p.sg_g1, p.sg_be1,
                                                     p.sg_m1, p.sg_v1,
                                                     p.part, p.cg_w1, p.cg_b1, p.cg_bng, p.cg_bnb,
                                                     p.cg_bnm, p.cg_bnv, p.cg_w2, p.cg_b2,
                                                     p.ec, p.s1);
        kMulF<<<dim3(1024), blk, 0, stream>>>(p.x1, p.x2, p.bn_g, p.bn_b, p.bn_m, p.bn_v,
                                              p.s1, p.sg_w2, p.sg_b2, p.sg_g2, p.sg_be2,
                                              p.sg_m2, p.sg_v2,
                                              p.sg_w3, p.sg_b3, p.ec, p.out0, p.outLL);
    }
}

// Round 15
// 103.545 us; speedup vs baseline: 3.6340x; 3.6340x over previous
//
#include <hip/hip_runtime.h>
#include <math.h>

#define EPSBN 1e-5f

typedef float f32x2 __attribute__((ext_vector_type(2)));
typedef float f32x4 __attribute__((ext_vector_type(4)));

constexpr int B   = 2;
constexpr int C1  = 60;           // x1 channels
constexpr int NV  = 64 * 64 * 64; // voxels per batch
constexpr int NBa = NV / 1024;    // kA: 256 blocks/batch (4 voxels/thread)
constexpr int NBc = NV / 256;     // conv kernels: 1024 blocks/batch (1 voxel/thread)

// ---------------------------------------------------------------------------
// Kernel A: DWT + BN + ReLU + conv0 (1x1x1, 64->4) + channel partials.
// Writes ONLY s0 (channel-last [b][voxel][4]) and part [b][64][NBa].
// ---------------------------------------------------------------------------
__global__ __launch_bounds__(256) void kA(
    const float* __restrict__ x1, const float* __restrict__ x2,
    const float* __restrict__ bn_g, const float* __restrict__ bn_b,
    const float* __restrict__ bn_m, const float* __restrict__ bn_v,
    const float* __restrict__ sg_w0, const float* __restrict__ sg_b0,
    const float* __restrict__ sg_g0, const float* __restrict__ sg_be0,
    const float* __restrict__ sg_m0, const float* __restrict__ sg_v0,
    float* __restrict__ s0,
    float* __restrict__ part)
{
    __shared__ float wsumq[64][65];

    const int tid = threadIdx.x;
    const int qid = tid >> 2;

    float dsc[4], dsh[4], c0A[4], c0B[4];
    #pragma unroll
    for (int r = 0; r < 4; ++r) {
        float d = bn_g[r] * rsqrtf(bn_v[r] + EPSBN);
        dsc[r] = d; dsh[r] = bn_b[r] - bn_m[r] * d;
        float sc = sg_g0[r] * rsqrtf(sg_v0[r] + EPSBN);
        c0A[r] = sc; c0B[r] = (sg_b0[r] - sg_m0[r]) * sc + sg_be0[r];
    }

    const int b = blockIdx.y;
    const int v = blockIdx.x * 1024 + tid * 4;
    const int x = v & 63, y = (v >> 6) & 63, z = v >> 12;

    const float* px2 = x2 + (size_t)b * (128 * 128 * 64);
    const size_t i00 = ((size_t)(2 * z) * 128 + 2 * y) * 64 + x;
    const float4 p00 = *(const float4*)(px2 + i00);
    const float4 p01 = *(const float4*)(px2 + i00 + 64);
    const float4 p10 = *(const float4*)(px2 + i00 + 8192);
    const float4 p11 = *(const float4*)(px2 + i00 + 8256);
    const float* q00 = (const float*)&p00; const float* q01 = (const float*)&p01;
    const float* q10 = (const float*)&p10; const float* q11 = (const float*)&p11;

    float tv[4][4];
    #pragma unroll
    for (int vi = 0; vi < 4; ++vi) {
        float a = q00[vi], bb = q01[vi], c = q10[vi], d = q11[vi];
        float LL = 0.5f * (a + bb + c + d);
        float LH = 0.5f * (a + bb - c - d);
        float HL = 0.5f * (a - bb + c - d);
        float HH = 0.5f * (a - bb - c + d);
        tv[vi][0] = fmaxf(LL * dsc[0] + dsh[0], 0.f);
        tv[vi][1] = fmaxf(LH * dsc[1] + dsh[1], 0.f);
        tv[vi][2] = fmaxf(HL * dsc[2] + dsh[2], 0.f);
        tv[vi][3] = fmaxf(HH * dsc[3] + dsh[3], 0.f);
    }

    float acc[4][4] = {};
    #pragma unroll
    for (int c = 0; c < 4; ++c) {
        #pragma unroll
        for (int vi = 0; vi < 4; ++vi) {
            float t = tv[vi][c];
            #pragma unroll
            for (int r = 0; r < 4; ++r) acc[vi][r] += sg_w0[r * 64 + c] * t;
        }
        float rs = tv[0][c] + tv[1][c] + tv[2][c] + tv[3][c];
        rs += __shfl_xor(rs, 1);
        rs += __shfl_xor(rs, 2);
        if ((tid & 3) == 0) wsumq[c][qid] = rs;
    }

    const float* px1 = x1 + (size_t)b * C1 * NV + v;
    #pragma unroll 4
    for (int c = 0; c < C1; ++c) {
        const float4 f = *(const float4*)(px1 + (size_t)c * NV);
        const float* fv = (const float*)&f;
        #pragma unroll
        for (int r = 0; r < 4; ++r) {
            const float w = sg_w0[r * 64 + 4 + c];
            #pragma unroll
            for (int vi = 0; vi < 4; ++vi) acc[vi][r] += w * fv[vi];
        }
        float rs = f.x + f.y + f.z + f.w;
        rs += __shfl_xor(rs, 1);
        rs += __shfl_xor(rs, 2);
        if ((tid & 3) == 0) wsumq[4 + c][qid] = rs;
    }

    float4* ps0 = (float4*)s0 + (size_t)b * NV + v;
    #pragma unroll
    for (int vi = 0; vi < 4; ++vi)
        ps0[vi] = make_float4(fmaxf(acc[vi][0] * c0A[0] + c0B[0], 0.f),
                              fmaxf(acc[vi][1] * c0A[1] + c0B[1], 0.f),
                              fmaxf(acc[vi][2] * c0A[2] + c0B[2], 0.f),
                              fmaxf(acc[vi][3] * c0A[3] + c0B[3], 0.f));

    __syncthreads();
    if (tid < 64) {
        const float* rowp = &wsumq[tid][0];
        float p = 0.f;
        #pragma unroll
        for (int i = 0; i < 64; ++i) p += rowp[i];
        part[((size_t)b * 64 + tid) * NBa + blockIdx.x] = p;
    }
}

// ---------------------------------------------------------------------------
// kConv1: dilated conv1 + BN + ReLU (1 voxel/thread, 1024 blocks/batch).
// Extra block (blockIdx.x == NBc) runs the channel-gate MLP -> ec = e^{-att_c}.
// ---------------------------------------------------------------------------
__global__ __launch_bounds__(256) void kConv1(
    const float* __restrict__ sin_,
    const float* __restrict__ w, const float* __restrict__ bias,
    const float* __restrict__ g, const float* __restrict__ be,
    const float* __restrict__ m, const float* __restrict__ vv,
    const float* __restrict__ part,
    const float* __restrict__ cg_w1, const float* __restrict__ cg_b1,
    const float* __restrict__ cg_bng, const float* __restrict__ cg_bnb,
    const float* __restrict__ cg_bnm, const float* __restrict__ cg_bnv,
    const float* __restrict__ cg_w2, const float* __restrict__ cg_b2,
    float* __restrict__ ec,
    float* __restrict__ outp)
{
    const int tid = threadIdx.x;
    const int b = blockIdx.y;

    if (blockIdx.x == NBc) {   // ---- channel-gate MLP ----
        __shared__ float pooled[64];
        __shared__ float h[4];
        const int c = tid >> 2, q = tid & 3;
        const float4* pp = (const float4*)(part + ((size_t)b * 64 + c) * NBa + q * 64);
        float sm = 0.f;
        #pragma unroll
        for (int i = 0; i < 16; ++i) { float4 f = pp[i]; sm += f.x + f.y + f.z + f.w; }
        sm += __shfl_xor(sm, 1);
        sm += __shfl_xor(sm, 2);
        if (q == 0) pooled[c] = sm * (1.0f / NV);
        __syncthreads();
        if (tid < 4) {
            float a = cg_b1[tid];
            for (int cc = 0; cc < 64; ++cc) a += pooled[cc] * cg_w1[tid * 64 + cc];
            float sc = cg_bng[tid] * rsqrtf(cg_bnv[tid] + EPSBN);
            h[tid] = fmaxf((a - cg_bnm[tid]) * sc + cg_bnb[tid], 0.f);
        }
        __syncthreads();
        if (tid < 64) {
            float a = cg_b2[tid];
            #pragma unroll
            for (int r = 0; r < 4; ++r) a += h[r] * cg_w2[tid * 4 + r];
            ec[b * 64 + tid] = __expf(-a);
        }
        return;
    }

    __shared__ float4 wl4[108];
    if (tid < 108) {
        const int t = tid >> 2, r = tid & 3;
        wl4[tid] = make_float4(w[r * 108 +      t], w[r * 108 +  27 + t],
                               w[r * 108 + 54 + t], w[r * 108 +  81 + t]);
    }
    float cAr[4], cBr[4];
    #pragma unroll
    for (int r = 0; r < 4; ++r) {
        float sc = g[r] * rsqrtf(vv[r] + EPSBN);
        cAr[r] = sc;
        cBr[r] = (bias[r] - m[r]) * sc + be[r];
    }
    __syncthreads();

    const int v = blockIdx.x * 256 + tid;
    const int x = v & 63, y = (v >> 6) & 63, z = v >> 12;
    const float4* pin = (const float4*)sin_ + (size_t)b * NV;

    float a0 = 0.f, a1 = 0.f, a2 = 0.f, a3 = 0.f;
    #pragma unroll
    for (int kz = -1; kz <= 1; ++kz) {
        const int zz = z + 4 * kz;
        if ((unsigned)zz >= 64u) continue;
        #pragma unroll
        for (int ky = -1; ky <= 1; ++ky) {
            const int yy = y + 4 * ky;
            if ((unsigned)yy >= 64u) continue;
            #pragma unroll
            for (int kx = -1; kx <= 1; ++kx) {
                const int xx = x + 4 * kx;
                if ((unsigned)xx >= 64u) continue;
                const int t = (kz + 1) * 9 + (ky + 1) * 3 + (kx + 1);
                const float4 tap = pin[zz * 4096 + yy * 64 + xx];
                const float4 w0 = wl4[t * 4 + 0];
                const float4 w1 = wl4[t * 4 + 1];
                const float4 w2 = wl4[t * 4 + 2];
                const float4 w3 = wl4[t * 4 + 3];
                a0 += w0.x * tap.x + w0.y * tap.y + w0.z * tap.z + w0.w * tap.w;
                a1 += w1.x * tap.x + w1.y * tap.y + w1.z * tap.z + w1.w * tap.w;
                a2 += w2.x * tap.x + w2.y * tap.y + w2.z * tap.z + w2.w * tap.w;
                a3 += w3.x * tap.x + w3.y * tap.y + w3.z * tap.z + w3.w * tap.w;
            }
        }
    }

    ((float4*)outp)[(size_t)b * NV + v] =
        make_float4(fmaxf(a0 * cAr[0] + cBr[0], 0.f),
                    fmaxf(a1 * cAr[1] + cBr[1], 0.f),
                    fmaxf(a2 * cAr[2] + cBr[2], 0.f),
                    fmaxf(a3 * cAr[3] + cBr[3], 0.f));
}

// ---------------------------------------------------------------------------
// kMulF: fused DWT-recompute + conv2(dil=4)+BN+ReLU + conv3 + sigmoid + scale.
// 256-voxel slices, 2048 blocks total (8/CU).
// Phase 1 (1 voxel/thread): DWT from x2 -> LL out + dwt in LDS; conv2 -> es.
// Phase 2: thread owns quad (tid&63) and 16 channels ((tid>>6)*16).
// ---------------------------------------------------------------------------
__global__ __launch_bounds__(256) void kMulF(
    const float* __restrict__ x1,
    const float* __restrict__ x2,
    const float* __restrict__ bn_g, const float* __restrict__ bn_b,
    const float* __restrict__ bn_m, const float* __restrict__ bn_v,
    const float* __restrict__ s1,
    const float* __restrict__ w, const float* __restrict__ bias,
    const float* __restrict__ g, const float* __restrict__ be,
    const float* __restrict__ m, const float* __restrict__ vv,
    const float* __restrict__ w3, const float* __restrict__ b3,
    const float* __restrict__ ec,
    float* __restrict__ out0,
    float* __restrict__ outLL)
{
    const int tid = threadIdx.x;
    const int b = blockIdx.x >> 10;                // grid.x = 2048
    const int vb = (blockIdx.x & 1023) * 256;      // base voxel of block

    __shared__ float4 wl4[108];
    __shared__ float ecs[64];
    __shared__ float esb[256];
    __shared__ float dwtb[256][4];
    if (tid < 108) {
        const int t = tid >> 2, r = tid & 3;
        wl4[tid] = make_float4(w[r * 108 +      t], w[r * 108 +  27 + t],
                               w[r * 108 + 54 + t], w[r * 108 +  81 + t]);
    }
    if (tid < 64) ecs[tid] = ec[b * 64 + tid];
    float cAr[4], cBr[4], w3l[4], dsc[4], dsh[4];
    #pragma unroll
    for (int r = 0; r < 4; ++r) {
        float sc = g[r] * rsqrtf(vv[r] + EPSBN);
        cAr[r] = sc;
        cBr[r] = (bias[r] - m[r]) * sc + be[r];
        w3l[r] = w3[r];
        float d = bn_g[r] * rsqrtf(bn_v[r] + EPSBN);
        dsc[r] = d; dsh[r] = bn_b[r] - bn_m[r] * d;
    }
    const float b3l = b3[0];
    __syncthreads();

    // ---- phase 1: DWT + conv2 for 1 voxel per thread ----
    {
        const int v = vb + tid;
        const int x = v & 63, y = (v >> 6) & 63, z = v >> 12;

        const float* px2 = x2 + (size_t)b * (128 * 128 * 64);
        const size_t i00 = ((size_t)(2 * z) * 128 + 2 * y) * 64 + x;
        const float a  = px2[i00],        bb = px2[i00 + 64];
        const float c  = px2[i00 + 8192], d  = px2[i00 + 8256];
        {
            float LL = 0.5f * (a + bb + c + d);
            float LH = 0.5f * (a + bb - c - d);
            float HL = 0.5f * (a - bb + c - d);
            float HH = 0.5f * (a - bb - c + d);
            float4 tv = make_float4(fmaxf(LL * dsc[0] + dsh[0], 0.f),
                                    fmaxf(LH * dsc[1] + dsh[1], 0.f),
                                    fmaxf(HL * dsc[2] + dsh[2], 0.f),
                                    fmaxf(HH * dsc[3] + dsh[3], 0.f));
            *(float4*)&dwtb[tid][0] = tv;
            __builtin_nontemporal_store(LL, outLL + (size_t)b * NV + v);
        }

        const float4* pin = (const float4*)s1 + (size_t)b * NV;
        float a0 = 0.f, a1 = 0.f, a2 = 0.f, a3 = 0.f;
        #pragma unroll
        for (int kz = -1; kz <= 1; ++kz) {
            const int zz = z + 4 * kz;
            if ((unsigned)zz >= 64u) continue;
            #pragma unroll
            for (int ky = -1; ky <= 1; ++ky) {
                const int yy = y + 4 * ky;
                if ((unsigned)yy >= 64u) continue;
                #pragma unroll
                for (int kx = -1; kx <= 1; ++kx) {
                    const int xx = x + 4 * kx;
                    if ((unsigned)xx >= 64u) continue;
                    const int t = (kz + 1) * 9 + (ky + 1) * 3 + (kx + 1);
                    const float4 tap = pin[zz * 4096 + yy * 64 + xx];
                    const float4 w0 = wl4[t * 4 + 0];
                    const float4 w1 = wl4[t * 4 + 1];
                    const float4 w2 = wl4[t * 4 + 2];
                    const float4 w3q = wl4[t * 4 + 3];
                    a0 += w0.x * tap.x + w0.y * tap.y + w0.z * tap.z + w0.w * tap.w;
                    a1 += w1.x * tap.x + w1.y * tap.y + w1.z * tap.z + w1.w * tap.w;
                    a2 += w2.x * tap.x + w2.y * tap.y + w2.z * tap.z + w2.w * tap.w;
                    a3 += w3q.x * tap.x + w3q.y * tap.y + w3q.z * tap.z + w3q.w * tap.w;
                }
            }
        }
        float r0 = fmaxf(a0 * cAr[0] + cBr[0], 0.f);
        float r1 = fmaxf(a1 * cAr[1] + cBr[1], 0.f);
        float r2 = fmaxf(a2 * cAr[2] + cBr[2], 0.f);
        float r3 = fmaxf(a3 * cAr[3] + cBr[3], 0.f);
        esb[tid] = __expf(-(b3l + w3l[0] * r0 + w3l[1] * r1 + w3l[2] * r2 + w3l[3] * r3));
    }
    __syncthreads();

    // ---- phase 2: out = in * (1 + 1/(1 + ec*es)) ----
    const int q = tid & 63;                   // quad within 256-voxel slice
    const int v = vb + q * 4;
    const int ch0 = (tid >> 6) * 16;          // wave-uniform channel group
    const float es0 = esb[q * 4 + 0], es1 = esb[q * 4 + 1];
    const float es2 = esb[q * 4 + 2], es3 = esb[q * 4 + 3];

    float* po = out0 + ((size_t)b * 64 + ch0) * NV + v;

    if (ch0 == 0) {          // wave-uniform branch: dwt channels 0..3 + x1 0..11
        float4 dq0 = *(const float4*)&dwtb[q * 4 + 0][0];
        float4 dq1 = *(const float4*)&dwtb[q * 4 + 1][0];
        float4 dq2 = *(const float4*)&dwtb[q * 4 + 2][0];
        float4 dq3 = *(const float4*)&dwtb[q * 4 + 3][0];
        const float dv0[4] = { dq0.x, dq0.y, dq0.z, dq0.w };
        const float dv1[4] = { dq1.x, dq1.y, dq1.z, dq1.w };
        const float dv2[4] = { dq2.x, dq2.y, dq2.z, dq2.w };
        const float dv3[4] = { dq3.x, dq3.y, dq3.z, dq3.w };
        #pragma unroll
        for (int cc = 0; cc < 4; ++cc) {
            const float e = ecs[cc];
            f32x4 o;
            o.x = dv0[cc] * (1.f + __builtin_amdgcn_rcpf(1.f + e * es0));
            o.y = dv1[cc] * (1.f + __builtin_amdgcn_rcpf(1.f + e * es1));
            o.z = dv2[cc] * (1.f + __builtin_amdgcn_rcpf(1.f + e * es2));
            o.w = dv3[cc] * (1.f + __builtin_amdgcn_rcpf(1.f + e * es3));
            __builtin_nontemporal_store(o, (f32x4*)(po + (size_t)cc * NV));
        }
        const float* px = x1 + (size_t)b * C1 * NV + v;
        #pragma unroll 6
        for (int cc = 4; cc < 16; ++cc) {
            const float4 in4 = *(const float4*)(px + (size_t)(cc - 4) * NV);
            const float e = ecs[cc];
            f32x4 o;
            o.x = in4.x * (1.f + __builtin_amdgcn_rcpf(1.f + e * es0));
            o.y = in4.y * (1.f + __builtin_amdgcn_rcpf(1.f + e * es1));
            o.z = in4.z * (1.f + __builtin_amdgcn_rcpf(1.f + e * es2));
            o.w = in4.w * (1.f + __builtin_amdgcn_rcpf(1.f + e * es3));
            __builtin_nontemporal_store(o, (f32x4*)(po + (size_t)cc * NV));
        }
    } else {                 // x1 channels ch0-4 .. ch0+11
        const float* px = x1 + ((size_t)b * C1 + (ch0 - 4)) * NV + v;
        #pragma unroll 8
        for (int cc = 0; cc < 16; ++cc) {
            const float4 in4 = *(const float4*)(px + (size_t)cc * NV);
            const float e = ecs[ch0 + cc];
            f32x4 o;
            o.x = in4.x * (1.f + __builtin_amdgcn_rcpf(1.f + e * es0));
            o.y = in4.y * (1.f + __builtin_amdgcn_rcpf(1.f + e * es1));
            o.z = in4.z * (1.f + __builtin_amdgcn_rcpf(1.f + e * es2));
            o.w = in4.w * (1.f + __builtin_amdgcn_rcpf(1.f + e * es3));
            __builtin_nontemporal_store(o, (f32x4*)(po + (size_t)cc * NV));
        }
    }
}

// ---------------------------------------------------------------------------
extern "C" void kernel_launch(void* const* d_in, const int* in_sizes, int n_in,
                              void* d_out, int out_size, void* d_ws, size_t ws_size,
                              hipStream_t stream)
{
    const float* x1 = (const float*)d_in[0];
    const float* x2 = (const float*)d_in[1];
    const float* bn_g = (const float*)d_in[2];
    const float* bn_b = (const float*)d_in[3];
    const float* bn_m = (const float*)d_in[4];
    const float* bn_v = (const float*)d_in[5];
    const float* cg_w1 = (const float*)d_in[6];
    const float* cg_b1 = (const float*)d_in[7];
    const float* cg_bng = (const float*)d_in[8];
    const float* cg_bnb = (const float*)d_in[9];
    const float* cg_bnm = (const float*)d_in[10];
    const float* cg_bnv = (const float*)d_in[11];
    const float* cg_w2 = (const float*)d_in[12];
    const float* cg_b2 = (const float*)d_in[13];
    const float* sg_w0 = (const float*)d_in[14];
    const float* sg_b0 = (const float*)d_in[15];
    const float* sg_g0 = (const float*)d_in[16];
    const float* sg_be0 = (const float*)d_in[17];
    const float* sg_m0 = (const float*)d_in[18];
    const float* sg_v0 = (const float*)d_in[19];
    const float* sg_w1 = (const float*)d_in[20];
    const float* sg_b1 = (const float*)d_in[21];
    const float* sg_g1 = (const float*)d_in[22];
    const float* sg_be1 = (const float*)d_in[23];
    const float* sg_m1 = (const float*)d_in[24];
    const float* sg_v1 = (const float*)d_in[25];
    const float* sg_w2 = (const float*)d_in[26];
    const float* sg_b2 = (const float*)d_in[27];
    const float* sg_g2 = (const float*)d_in[28];
    const float* sg_be2 = (const float*)d_in[29];
    const float* sg_m2 = (const float*)d_in[30];
    const float* sg_v2 = (const float*)d_in[31];
    const float* sg_w3 = (const float*)d_in[32];
    const float* sg_b3 = (const float*)d_in[33];

    float* ws = (float*)d_ws;
    float* s0   = ws;                 // 2,097,152
    float* s1   = ws + 2097152;       // 2,097,152
    float* part = ws + 4194304;       // B*64*NBa = 32,768
    float* ec   = ws + 4227072;       // 128

    float* out0  = (float*)d_out;
    float* outLL = out0 + (size_t)B * 64 * NV;

    dim3 blk(256);
    kA<<<dim3(NBa, B), blk, 0, stream>>>(x1, x2, bn_g, bn_b, bn_m, bn_v,
                                         sg_w0, sg_b0, sg_g0, sg_be0, sg_m0, sg_v0,
                                         s0, part);
    kConv1<<<dim3(NBc + 1, B), blk, 0, stream>>>(s0, sg_w1, sg_b1, sg_g1, sg_be1, sg_m1, sg_v1,
                                                 part, cg_w1, cg_b1, cg_bng, cg_bnb, cg_bnm, cg_bnv,
                                                 cg_w2, cg_b2, ec, s1);
    kMulF<<<dim3(2048), blk, 0, stream>>>(x1, x2, bn_g, bn_b, bn_m, bn_v,
                                          s1, sg_w2, sg_b2, sg_g2, sg_be2, sg_m2, sg_v2,
                                          sg_w3, sg_b3, ec, out0, outLL);
}

// Round 16
// 98.920 us; speedup vs baseline: 3.8039x; 1.0467x over previous
//
#include <hip/hip_runtime.h>
#include <math.h>

#define EPSBN 1e-5f

typedef float f32x2 __attribute__((ext_vector_type(2)));
typedef float f32x4 __attribute__((ext_vector_type(4)));

constexpr int B   = 2;
constexpr int C1  = 60;           // x1 channels
constexpr int NV  = 64 * 64 * 64; // voxels per batch
constexpr int NBa = NV / 1024;    // kA: 256 blocks/batch (4 voxels/thread)
constexpr int NBc = NV / 512;     // conv1: 512 blocks/batch (2 voxels/thread)

// ---------------------------------------------------------------------------
// Kernel A: DWT + BN + ReLU + conv0 (1x1x1, 64->4) + channel partials.
// Writes ONLY s0 (channel-last [b][voxel][4]) and part [b][64][NBa].
// dwt/LL are recomputed in kMulF (cheap; saves the dwtM HBM round trip).
// ---------------------------------------------------------------------------
__global__ __launch_bounds__(256) void kA(
    const float* __restrict__ x1, const float* __restrict__ x2,
    const float* __restrict__ bn_g, const float* __restrict__ bn_b,
    const float* __restrict__ bn_m, const float* __restrict__ bn_v,
    const float* __restrict__ sg_w0, const float* __restrict__ sg_b0,
    const float* __restrict__ sg_g0, const float* __restrict__ sg_be0,
    const float* __restrict__ sg_m0, const float* __restrict__ sg_v0,
    float* __restrict__ s0,
    float* __restrict__ part)
{
    __shared__ float wsumq[64][65];   // [channel][quad]  (pad vs bank conflicts)

    const int tid = threadIdx.x;
    const int qid = tid >> 2;

    // per-thread BN constants (registers, no LDS)
    float dsc[4], dsh[4], c0A[4], c0B[4];
    #pragma unroll
    for (int r = 0; r < 4; ++r) {
        float d = bn_g[r] * rsqrtf(bn_v[r] + EPSBN);
        dsc[r] = d; dsh[r] = bn_b[r] - bn_m[r] * d;
        float sc = sg_g0[r] * rsqrtf(sg_v0[r] + EPSBN);
        c0A[r] = sc; c0B[r] = (sg_b0[r] - sg_m0[r]) * sc + sg_be0[r];
    }

    const int b = blockIdx.y;
    const int v = blockIdx.x * 1024 + tid * 4;  // 4-aligned x
    const int x = v & 63, y = (v >> 6) & 63, z = v >> 12;

    // Haar DWT2 over (D,H): 4 consecutive x per thread
    const float* px2 = x2 + (size_t)b * (128 * 128 * 64);
    const size_t i00 = ((size_t)(2 * z) * 128 + 2 * y) * 64 + x;
    const float4 p00 = *(const float4*)(px2 + i00);
    const float4 p01 = *(const float4*)(px2 + i00 + 64);
    const float4 p10 = *(const float4*)(px2 + i00 + 8192);
    const float4 p11 = *(const float4*)(px2 + i00 + 8256);
    const float* q00 = (const float*)&p00; const float* q01 = (const float*)&p01;
    const float* q10 = (const float*)&p10; const float* q11 = (const float*)&p11;

    float tv[4][4];
    #pragma unroll
    for (int vi = 0; vi < 4; ++vi) {
        float a = q00[vi], bb = q01[vi], c = q10[vi], d = q11[vi];
        float LL = 0.5f * (a + bb + c + d);
        float LH = 0.5f * (a + bb - c - d);
        float HL = 0.5f * (a - bb + c - d);
        float HH = 0.5f * (a - bb - c + d);
        tv[vi][0] = fmaxf(LL * dsc[0] + dsh[0], 0.f);
        tv[vi][1] = fmaxf(LH * dsc[1] + dsh[1], 0.f);
        tv[vi][2] = fmaxf(HL * dsc[2] + dsh[2], 0.f);
        tv[vi][3] = fmaxf(HH * dsc[3] + dsh[3], 0.f);
    }

    float acc[4][4] = {};
    #pragma unroll
    for (int c = 0; c < 4; ++c) {
        #pragma unroll
        for (int vi = 0; vi < 4; ++vi) {
            float t = tv[vi][c];
            #pragma unroll
            for (int r = 0; r < 4; ++r) acc[vi][r] += sg_w0[r * 64 + c] * t;
        }
        float rs = tv[0][c] + tv[1][c] + tv[2][c] + tv[3][c];
        rs += __shfl_xor(rs, 1);
        rs += __shfl_xor(rs, 2);
        if ((tid & 3) == 0) wsumq[c][qid] = rs;
    }

    const float* px1 = x1 + (size_t)b * C1 * NV + v;
    #pragma unroll 4
    for (int c = 0; c < C1; ++c) {
        const float4 f = *(const float4*)(px1 + (size_t)c * NV);
        const float* fv = (const float*)&f;
        #pragma unroll
        for (int r = 0; r < 4; ++r) {
            const float w = sg_w0[r * 64 + 4 + c];   // uniform -> s_load
            #pragma unroll
            for (int vi = 0; vi < 4; ++vi) acc[vi][r] += w * fv[vi];
        }
        float rs = f.x + f.y + f.z + f.w;
        rs += __shfl_xor(rs, 1);
        rs += __shfl_xor(rs, 2);
        if ((tid & 3) == 0) wsumq[4 + c][qid] = rs;
    }

    float4* ps0 = (float4*)s0 + (size_t)b * NV + v;
    #pragma unroll
    for (int vi = 0; vi < 4; ++vi)
        ps0[vi] = make_float4(fmaxf(acc[vi][0] * c0A[0] + c0B[0], 0.f),
                              fmaxf(acc[vi][1] * c0A[1] + c0B[1], 0.f),
                              fmaxf(acc[vi][2] * c0A[2] + c0B[2], 0.f),
                              fmaxf(acc[vi][3] * c0A[3] + c0B[3], 0.f));

    __syncthreads();
    if (tid < 64) {
        const float* rowp = &wsumq[tid][0];
        float p = 0.f;
        #pragma unroll
        for (int i = 0; i < 64; ++i) p += rowp[i];
        part[((size_t)b * 64 + tid) * NBa + blockIdx.x] = p;
    }
}

// ---------------------------------------------------------------------------
// kConv1: dilated conv1 + BN + ReLU (2 voxels/thread).
// Extra block (blockIdx.x == NBc) runs the channel-gate MLP -> ec = e^{-att_c}.
// ---------------------------------------------------------------------------
__global__ __launch_bounds__(256) void kConv1(
    const float* __restrict__ sin_,
    const float* __restrict__ w, const float* __restrict__ bias,
    const float* __restrict__ g, const float* __restrict__ be,
    const float* __restrict__ m, const float* __restrict__ vv,
    const float* __restrict__ part,
    const float* __restrict__ cg_w1, const float* __restrict__ cg_b1,
    const float* __restrict__ cg_bng, const float* __restrict__ cg_bnb,
    const float* __restrict__ cg_bnm, const float* __restrict__ cg_bnv,
    const float* __restrict__ cg_w2, const float* __restrict__ cg_b2,
    float* __restrict__ ec,
    float* __restrict__ outp)
{
    const int tid = threadIdx.x;
    const int b = blockIdx.y;

    if (blockIdx.x == NBc) {   // ---- channel-gate MLP ----
        __shared__ float pooled[64];
        __shared__ float h[4];
        const int c = tid >> 2, q = tid & 3;
        const float4* pp = (const float4*)(part + ((size_t)b * 64 + c) * NBa + q * 64);
        float sm = 0.f;
        #pragma unroll
        for (int i = 0; i < 16; ++i) { float4 f = pp[i]; sm += f.x + f.y + f.z + f.w; }
        sm += __shfl_xor(sm, 1);
        sm += __shfl_xor(sm, 2);
        if (q == 0) pooled[c] = sm * (1.0f / NV);
        __syncthreads();
        if (tid < 4) {
            float a = cg_b1[tid];
            for (int cc = 0; cc < 64; ++cc) a += pooled[cc] * cg_w1[tid * 64 + cc];
            float sc = cg_bng[tid] * rsqrtf(cg_bnv[tid] + EPSBN);
            h[tid] = fmaxf((a - cg_bnm[tid]) * sc + cg_bnb[tid], 0.f);
        }
        __syncthreads();
        if (tid < 64) {
            float a = cg_b2[tid];
            #pragma unroll
            for (int r = 0; r < 4; ++r) a += h[r] * cg_w2[tid * 4 + r];
            ec[b * 64 + tid] = __expf(-a);
        }
        return;
    }

    __shared__ float4 wl4[108];      // [t*4 + r]
    if (tid < 108) {
        const int t = tid >> 2, r = tid & 3;
        wl4[tid] = make_float4(w[r * 108 +      t], w[r * 108 +  27 + t],
                               w[r * 108 + 54 + t], w[r * 108 +  81 + t]);
    }
    float cAr[4], cBr[4];
    #pragma unroll
    for (int r = 0; r < 4; ++r) {
        float sc = g[r] * rsqrtf(vv[r] + EPSBN);
        cAr[r] = sc;
        cBr[r] = (bias[r] - m[r]) * sc + be[r];
    }
    __syncthreads();

    const int v = blockIdx.x * 512 + tid * 2;
    const int x = v & 63, y = (v >> 6) & 63, z = v >> 12;
    const float4* pin = (const float4*)sin_ + (size_t)b * NV;

    float acc[2][4] = {};
    #pragma unroll
    for (int kz = -1; kz <= 1; ++kz) {
        const int zz = z + 4 * kz;
        if ((unsigned)zz >= 64u) continue;
        #pragma unroll
        for (int ky = -1; ky <= 1; ++ky) {
            const int yy = y + 4 * ky;
            if ((unsigned)yy >= 64u) continue;
            #pragma unroll
            for (int kx = -1; kx <= 1; ++kx) {
                const int xx = x + 4 * kx;
                if ((unsigned)xx >= 64u) continue;
                const int t = (kz + 1) * 9 + (ky + 1) * 3 + (kx + 1);
                const int vt = zz * 4096 + yy * 64 + xx;
                const float4 w0 = wl4[t * 4 + 0];
                const float4 w1 = wl4[t * 4 + 1];
                const float4 w2 = wl4[t * 4 + 2];
                const float4 w3 = wl4[t * 4 + 3];
                #pragma unroll
                for (int vi = 0; vi < 2; ++vi) {
                    const float4 tap = pin[vt + vi];
                    acc[vi][0] += w0.x * tap.x + w0.y * tap.y + w0.z * tap.z + w0.w * tap.w;
                    acc[vi][1] += w1.x * tap.x + w1.y * tap.y + w1.z * tap.z + w1.w * tap.w;
                    acc[vi][2] += w2.x * tap.x + w2.y * tap.y + w2.z * tap.z + w2.w * tap.w;
                    acc[vi][3] += w3.x * tap.x + w3.y * tap.y + w3.z * tap.z + w3.w * tap.w;
                }
            }
        }
    }

    float4* po = (float4*)outp + (size_t)b * NV + v;
    #pragma unroll
    for (int vi = 0; vi < 2; ++vi)
        po[vi] = make_float4(fmaxf(acc[vi][0] * cAr[0] + cBr[0], 0.f),
                             fmaxf(acc[vi][1] * cAr[1] + cBr[1], 0.f),
                             fmaxf(acc[vi][2] * cAr[2] + cBr[2], 0.f),
                             fmaxf(acc[vi][3] * cAr[3] + cBr[3], 0.f));
}

// ---------------------------------------------------------------------------
// kMulF: fused DWT-recompute + conv2(dil=4)+BN+ReLU + conv3 + sigmoid + scale.
// Phase 1 (2 voxels/thread): DWT from x2 -> LL out (nt) + dwt channels in LDS;
//                            conv2 on s1 -> es in LDS.
// Phase 2: thread owns quad (tid&127) and 32 channels ((tid>>7)*32);
//          wave-uniform split: ch0==0 takes dwt channels from LDS.
// ---------------------------------------------------------------------------
__global__ __launch_bounds__(256) void kMulF(
    const float* __restrict__ x1,
    const float* __restrict__ x2,
    const float* __restrict__ bn_g, const float* __restrict__ bn_b,
    const float* __restrict__ bn_m, const float* __restrict__ bn_v,
    const float* __restrict__ s1,
    const float* __restrict__ w, const float* __restrict__ bias,
    const float* __restrict__ g, const float* __restrict__ be,
    const float* __restrict__ m, const float* __restrict__ vv,
    const float* __restrict__ w3, const float* __restrict__ b3,
    const float* __restrict__ ec,
    float* __restrict__ out0,
    float* __restrict__ outLL)
{
    const int tid = threadIdx.x;
    const int b = blockIdx.x >> 9;                 // grid.x = 1024
    const int vb = (blockIdx.x & 511) * 512;       // base voxel of block

    __shared__ float4 wl4[108];
    __shared__ float ecs[64];
    __shared__ float esb[512];
    __shared__ float dwtb[512][4];
    if (tid < 108) {
        const int t = tid >> 2, r = tid & 3;
        wl4[tid] = make_float4(w[r * 108 +      t], w[r * 108 +  27 + t],
                               w[r * 108 + 54 + t], w[r * 108 +  81 + t]);
    }
    if (tid < 64) ecs[tid] = ec[b * 64 + tid];
    float cAr[4], cBr[4], w3l[4], dsc[4], dsh[4];
    #pragma unroll
    for (int r = 0; r < 4; ++r) {
        float sc = g[r] * rsqrtf(vv[r] + EPSBN);
        cAr[r] = sc;
        cBr[r] = (bias[r] - m[r]) * sc + be[r];
        w3l[r] = w3[r];
        float d = bn_g[r] * rsqrtf(bn_v[r] + EPSBN);
        dsc[r] = d; dsh[r] = bn_b[r] - bn_m[r] * d;
    }
    const float b3l = b3[0];
    __syncthreads();

    // ---- phase 1: DWT + conv2 for 2 voxels per thread ----
    {
        const int v = vb + tid * 2;                // even x
        const int x = v & 63, y = (v >> 6) & 63, z = v >> 12;

        // DWT from x2 (L3-warm) -> LL out + BN'd channels in LDS
        const float* px2 = x2 + (size_t)b * (128 * 128 * 64);
        const size_t i00 = ((size_t)(2 * z) * 128 + 2 * y) * 64 + x;
        const float2 p00 = *(const float2*)(px2 + i00);
        const float2 p01 = *(const float2*)(px2 + i00 + 64);
        const float2 p10 = *(const float2*)(px2 + i00 + 8192);
        const float2 p11 = *(const float2*)(px2 + i00 + 8256);
        const float* q00 = (const float*)&p00; const float* q01 = (const float*)&p01;
        const float* q10 = (const float*)&p10; const float* q11 = (const float*)&p11;
        float llv[2];
        #pragma unroll
        for (int vi = 0; vi < 2; ++vi) {
            float a = q00[vi], bb = q01[vi], c = q10[vi], d = q11[vi];
            float LL = 0.5f * (a + bb + c + d);
            float LH = 0.5f * (a + bb - c - d);
            float HL = 0.5f * (a - bb + c - d);
            float HH = 0.5f * (a - bb - c + d);
            llv[vi] = LL;
            float4 tv = make_float4(fmaxf(LL * dsc[0] + dsh[0], 0.f),
                                    fmaxf(LH * dsc[1] + dsh[1], 0.f),
                                    fmaxf(HL * dsc[2] + dsh[2], 0.f),
                                    fmaxf(HH * dsc[3] + dsh[3], 0.f));
            *(float4*)&dwtb[tid * 2 + vi][0] = tv;
        }
        {
            f32x2 ll2 = { llv[0], llv[1] };
            __builtin_nontemporal_store(ll2, (f32x2*)(outLL + (size_t)b * NV + v));
        }

        // conv2
        const float4* pin = (const float4*)s1 + (size_t)b * NV;
        float acc[2][4] = {};
        #pragma unroll
        for (int kz = -1; kz <= 1; ++kz) {
            const int zz = z + 4 * kz;
            if ((unsigned)zz >= 64u) continue;
            #pragma unroll
            for (int ky = -1; ky <= 1; ++ky) {
                const int yy = y + 4 * ky;
                if ((unsigned)yy >= 64u) continue;
                #pragma unroll
                for (int kx = -1; kx <= 1; ++kx) {
                    const int xx = x + 4 * kx;     // x even -> xx+1 in-bounds iff xx is
                    if ((unsigned)xx >= 64u) continue;
                    const int t = (kz + 1) * 9 + (ky + 1) * 3 + (kx + 1);
                    const int vt = zz * 4096 + yy * 64 + xx;
                    const float4 w0 = wl4[t * 4 + 0];
                    const float4 w1 = wl4[t * 4 + 1];
                    const float4 w2 = wl4[t * 4 + 2];
                    const float4 w3q = wl4[t * 4 + 3];
                    #pragma unroll
                    for (int vi = 0; vi < 2; ++vi) {
                        const float4 tap = pin[vt + vi];
                        acc[vi][0] += w0.x * tap.x + w0.y * tap.y + w0.z * tap.z + w0.w * tap.w;
                        acc[vi][1] += w1.x * tap.x + w1.y * tap.y + w1.z * tap.z + w1.w * tap.w;
                        acc[vi][2] += w2.x * tap.x + w2.y * tap.y + w2.z * tap.z + w2.w * tap.w;
                        acc[vi][3] += w3q.x * tap.x + w3q.y * tap.y + w3q.z * tap.z + w3q.w * tap.w;
                    }
                }
            }
        }
        #pragma unroll
        for (int vi = 0; vi < 2; ++vi) {
            float r0 = fmaxf(acc[vi][0] * cAr[0] + cBr[0], 0.f);
            float r1 = fmaxf(acc[vi][1] * cAr[1] + cBr[1], 0.f);
            float r2 = fmaxf(acc[vi][2] * cAr[2] + cBr[2], 0.f);
            float r3 = fmaxf(acc[vi][3] * cAr[3] + cBr[3], 0.f);
            esb[tid * 2 + vi] =
                __expf(-(b3l + w3l[0] * r0 + w3l[1] * r1 + w3l[2] * r2 + w3l[3] * r3));
        }
    }
    __syncthreads();

    // ---- phase 2: out = in * (1 + 1/(1 + ec*es)) ----
    const int q = tid & 127;                 // quad within block
    const int v = vb + q * 4;
    const int ch0 = (tid >> 7) * 32;         // 0 for waves 0-1, 32 for waves 2-3
    const float es0 = esb[q * 4 + 0], es1 = esb[q * 4 + 1];
    const float es2 = esb[q * 4 + 2], es3 = esb[q * 4 + 3];

    float* po = out0 + ((size_t)b * 64 + ch0) * NV + v;

    if (ch0 == 0) {          // wave-uniform branch
        // channels 0..3 from LDS dwt
        float4 dq0 = *(const float4*)&dwtb[q * 4 + 0][0];
        float4 dq1 = *(const float4*)&dwtb[q * 4 + 1][0];
        float4 dq2 = *(const float4*)&dwtb[q * 4 + 2][0];
        float4 dq3 = *(const float4*)&dwtb[q * 4 + 3][0];
        const float dv0[4] = { dq0.x, dq0.y, dq0.z, dq0.w };
        const float dv1[4] = { dq1.x, dq1.y, dq1.z, dq1.w };
        const float dv2[4] = { dq2.x, dq2.y, dq2.z, dq2.w };
        const float dv3[4] = { dq3.x, dq3.y, dq3.z, dq3.w };
        #pragma unroll
        for (int cc = 0; cc < 4; ++cc) {
            const float e = ecs[cc];
            f32x4 o;
            o.x = dv0[cc] * (1.f + __builtin_amdgcn_rcpf(1.f + e * es0));
            o.y = dv1[cc] * (1.f + __builtin_amdgcn_rcpf(1.f + e * es1));
            o.z = dv2[cc] * (1.f + __builtin_amdgcn_rcpf(1.f + e * es2));
            o.w = dv3[cc] * (1.f + __builtin_amdgcn_rcpf(1.f + e * es3));
            __builtin_nontemporal_store(o, (f32x4*)(po + (size_t)cc * NV));
        }
        const float* px = x1 + (size_t)b * C1 * NV + v;
        #pragma unroll 7
        for (int cc = 4; cc < 32; ++cc) {
            const float4 in4 = *(const float4*)(px + (size_t)(cc - 4) * NV);
            const float e = ecs[cc];
            f32x4 o;
            o.x = in4.x * (1.f + __builtin_amdgcn_rcpf(1.f + e * es0));
            o.y = in4.y * (1.f + __builtin_amdgcn_rcpf(1.f + e * es1));
            o.z = in4.z * (1.f + __builtin_amdgcn_rcpf(1.f + e * es2));
            o.w = in4.w * (1.f + __builtin_amdgcn_rcpf(1.f + e * es3));
            __builtin_nontemporal_store(o, (f32x4*)(po + (size_t)cc * NV));
        }
    } else {
        const float* px = x1 + ((size_t)b * C1 + 28) * NV + v;
        #pragma unroll 8
        for (int cc = 0; cc < 32; ++cc) {
            const float4 in4 = *(const float4*)(px + (size_t)cc * NV);
            const float e = ecs[32 + cc];
            f32x4 o;
            o.x = in4.x * (1.f + __builtin_amdgcn_rcpf(1.f + e * es0));
            o.y = in4.y * (1.f + __builtin_amdgcn_rcpf(1.f + e * es1));
            o.z = in4.z * (1.f + __builtin_amdgcn_rcpf(1.f + e * es2));
            o.w = in4.w * (1.f + __builtin_amdgcn_rcpf(1.f + e * es3));
            __builtin_nontemporal_store(o, (f32x4*)(po + (size_t)cc * NV));
        }
    }
}

// ---------------------------------------------------------------------------
extern "C" void kernel_launch(void* const* d_in, const int* in_sizes, int n_in,
                              void* d_out, int out_size, void* d_ws, size_t ws_size,
                              hipStream_t stream)
{
    const float* x1 = (const float*)d_in[0];
    const float* x2 = (const float*)d_in[1];
    const float* bn_g = (const float*)d_in[2];
    const float* bn_b = (const float*)d_in[3];
    const float* bn_m = (const float*)d_in[4];
    const float* bn_v = (const float*)d_in[5];
    const float* cg_w1 = (const float*)d_in[6];
    const float* cg_b1 = (const float*)d_in[7];
    const float* cg_bng = (const float*)d_in[8];
    const float* cg_bnb = (const float*)d_in[9];
    const float* cg_bnm = (const float*)d_in[10];
    const float* cg_bnv = (const float*)d_in[11];
    const float* cg_w2 = (const float*)d_in[12];
    const float* cg_b2 = (const float*)d_in[13];
    const float* sg_w0 = (const float*)d_in[14];
    const float* sg_b0 = (const float*)d_in[15];
    const float* sg_g0 = (const float*)d_in[16];
    const float* sg_be0 = (const float*)d_in[17];
    const float* sg_m0 = (const float*)d_in[18];
    const float* sg_v0 = (const float*)d_in[19];
    const float* sg_w1 = (const float*)d_in[20];
    const float* sg_b1 = (const float*)d_in[21];
    const float* sg_g1 = (const float*)d_in[22];
    const float* sg_be1 = (const float*)d_in[23];
    const float* sg_m1 = (const float*)d_in[24];
    const float* sg_v1 = (const float*)d_in[25];
    const float* sg_w2 = (const float*)d_in[26];
    const float* sg_b2 = (const float*)d_in[27];
    const float* sg_g2 = (const float*)d_in[28];
    const float* sg_be2 = (const float*)d_in[29];
    const float* sg_m2 = (const float*)d_in[30];
    const float* sg_v2 = (const float*)d_in[31];
    const float* sg_w3 = (const float*)d_in[32];
    const float* sg_b3 = (const float*)d_in[33];

    float* ws = (float*)d_ws;
    float* s0   = ws;                 // 2,097,152
    float* s1   = ws + 2097152;       // 2,097,152
    float* part = ws + 4194304;       // B*64*NBa = 32,768
    float* ec   = ws + 4227072;       // 128

    float* out0  = (float*)d_out;
    float* outLL = out0 + (size_t)B * 64 * NV;

    dim3 blk(256);
    kA<<<dim3(NBa, B), blk, 0, stream>>>(x1, x2, bn_g, bn_b, bn_m, bn_v,
                                         sg_w0, sg_b0, sg_g0, sg_be0, sg_m0, sg_v0,
                                         s0, part);
    kConv1<<<dim3(NBc + 1, B), blk, 0, stream>>>(s0, sg_w1, sg_b1, sg_g1, sg_be1, sg_m1, sg_v1,
                                                 part, cg_w1, cg_b1, cg_bng, cg_bnb, cg_bnm, cg_bnv,
                                                 cg_w2, cg_b2, ec, s1);
    kMulF<<<dim3(1024), blk, 0, stream>>>(x1, x2, bn_g, bn_b, bn_m, bn_v,
                                          s1, sg_w2, sg_b2, sg_g2, sg_be2, sg_m2, sg_v2,
                                          sg_w3, sg_b3, ec, out0, outLL);
}